// Round 1
// 857.692 us; speedup vs baseline: 1.2906x; 1.2906x over previous
//
#include <hip/hip_runtime.h>
#include <math.h>

#define B_GROUPS 64
#define C_DIM 256
#define IN_DIM 512
#define EMB_DIM 512
#define NHEADS 8
#define HDIM 32

// ---------------- per-group starts via binary search ----------------
__global__ void starts_kernel(const int* __restrict__ bx, int nx,
                              const int* __restrict__ be, int ne,
                              int* __restrict__ sx, int* __restrict__ se) {
  int b = threadIdx.x;
  if (b > B_GROUPS) return;
  int lo = 0, hi = nx;
  while (lo < hi) { int mid = (lo + hi) >> 1; if (bx[mid] < b) lo = mid + 1; else hi = mid; }
  sx[b] = lo;
  lo = 0; hi = ne;
  while (lo < hi) { int mid = (lo + hi) >> 1; if (be[mid] < b) lo = mid + 1; else hi = mid; }
  se[b] = lo;
}

// ---------------- generic fp32 tiled GEMM: C = act(A@W + bias) ----------------
// A[M,K] row-major, W[K,N] row-major, bias[N]. ACT: 0=none, 1=exact GELU.
template<int ACT>
__global__ __launch_bounds__(256) void gemm_kernel(const float* __restrict__ A,
    const float* __restrict__ W, const float* __restrict__ bias,
    float* __restrict__ C, int M, int N, int K) {
  const int BM = 64, BN = 64, BK = 16;
  __shared__ float As[BK][68];   // transposed A tile, 68 -> 16B-aligned rows
  __shared__ float Ws[BK][BN];
  int bm = blockIdx.y * BM, bn = blockIdx.x * BN;
  int tid = threadIdx.x;
  int tx = tid & 15, ty = tid >> 4;
  float acc[4][4] = {};
  for (int k0 = 0; k0 < K; k0 += BK) {
    {
      int r = tid >> 2;            // 0..63
      int c = (tid & 3) * 4;       // 0,4,8,12
      int gr = bm + r;
      float4 av = make_float4(0.f, 0.f, 0.f, 0.f);
      if (gr < M) av = *(const float4*)&A[(size_t)gr * K + k0 + c];
      As[c + 0][r] = av.x; As[c + 1][r] = av.y; As[c + 2][r] = av.z; As[c + 3][r] = av.w;
    }
    {
      int r = tid >> 4;            // 0..15
      int c = (tid & 15) * 4;      // 0..60
      float4 wv = *(const float4*)&W[(size_t)(k0 + r) * N + bn + c];
      *(float4*)&Ws[r][c] = wv;
    }
    __syncthreads();
#pragma unroll
    for (int kk = 0; kk < BK; ++kk) {
      float a[4], w[4];
#pragma unroll
      for (int i = 0; i < 4; ++i) a[i] = As[kk][ty * 4 + i];
#pragma unroll
      for (int i = 0; i < 4; ++i) w[i] = Ws[kk][tx * 4 + i];
#pragma unroll
      for (int i = 0; i < 4; ++i)
#pragma unroll
        for (int j = 0; j < 4; ++j) acc[i][j] += a[i] * w[j];
    }
    __syncthreads();
  }
#pragma unroll
  for (int i = 0; i < 4; ++i) {
    int gr = bm + ty * 4 + i;
    if (gr >= M) continue;
#pragma unroll
    for (int j = 0; j < 4; ++j) {
      int gc = bn + tx * 4 + j;
      float v = acc[i][j] + bias[gc];
      if (ACT == 1) v = 0.5f * v * (1.0f + erff(v * 0.70710678118654752f));
      C[(size_t)gr * N + gc] = v;
    }
  }
}

// ---------------- LayerNorm over last dim (256), in-place ----------------
__global__ __launch_bounds__(256) void ln_kernel(float* __restrict__ h,
    const float* __restrict__ w, const float* __restrict__ b, int M) {
  int row = blockIdx.x * 4 + (threadIdx.x >> 6);
  int lane = threadIdx.x & 63;
  if (row >= M) return;
  float4 v = *(const float4*)&h[(size_t)row * C_DIM + lane * 4];
  float s  = v.x + v.y + v.z + v.w;
  float s2 = v.x * v.x + v.y * v.y + v.z * v.z + v.w * v.w;
#pragma unroll
  for (int off = 1; off < 64; off <<= 1) { s += __shfl_xor(s, off); s2 += __shfl_xor(s2, off); }
  float mu  = s  * (1.0f / 256.0f);
  float var = s2 * (1.0f / 256.0f) - mu * mu;
  float inv = rsqrtf(var + 1e-5f);
  float4 wv = *(const float4*)&w[lane * 4];
  float4 bv = *(const float4*)&b[lane * 4];
  float4 o;
  o.x = (v.x - mu) * inv * wv.x + bv.x;
  o.y = (v.y - mu) * inv * wv.y + bv.y;
  o.z = (v.z - mu) * inv * wv.z + bv.z;
  o.w = (v.w - mu) * inv * wv.w + bv.w;
  *(float4*)&h[(size_t)row * C_DIM + lane * 4] = o;
}

// ---------------- ragged masked flash attention (v2) ----------------
// grid: (8 q-tiles of 64, B, NH); block 256 (4 waves).
// Thread (qg = tid>>3, j = tid&7): owns q-rows {qg, qg+32}, value dims j*4..j*4+3,
// and score columns j*8..j*8+7.
// LDS layouts chosen for bank behavior:
//   KsT[32][68]: transposed K tile; score-loop reads 8 distinct float4 addrs
//                spread over 4 bank-group positions (2-way, free).
//   Ps[64][68] : stride-68 pad -> 8 distinct qrows hit 8 distinct positions.
//   Vs[64][36] : PV float4 reads: 8 distinct j -> 8 distinct positions.
__global__ __launch_bounds__(256) void attn_kernel(const float* __restrict__ q,
    const float* __restrict__ k, const float* __restrict__ v,
    const int* __restrict__ sx, const int* __restrict__ se,
    const int* __restrict__ emask, float* __restrict__ y) {
  int b = blockIdx.y, hd = blockIdx.z, qt = blockIdx.x;
  int xs = sx[b], lx = sx[b + 1] - xs;
  if (qt * 64 >= lx) return;
  int es = se[b], le = se[b + 1] - es;

  __shared__ float KsT[32][68];
  __shared__ float Vs[64][36];
  __shared__ float Ps[64][68];
  __shared__ int   Mk[64];

  int tid = threadIdx.x;
  int j  = tid & 7;    // value-dim / score-col group
  int qg = tid >> 3;   // 0..31

  // Q rows -> registers (8 lanes share each row; HW merges same-address lanes)
  float qreg[2][32];
#pragma unroll
  for (int rr = 0; rr < 2; ++rr) {
    int qr = qt * 64 + qg + rr * 32;
    if (qr < lx) {
      const float* qp = &q[(size_t)(xs + qr) * C_DIM + hd * HDIM];
#pragma unroll
      for (int d4 = 0; d4 < 8; ++d4) {
        float4 t4 = *(const float4*)&qp[d4 * 4];
        qreg[rr][d4 * 4 + 0] = t4.x; qreg[rr][d4 * 4 + 1] = t4.y;
        qreg[rr][d4 * 4 + 2] = t4.z; qreg[rr][d4 * 4 + 3] = t4.w;
      }
    } else {
#pragma unroll
      for (int d = 0; d < 32; ++d) qreg[rr][d] = 0.f;
    }
  }

  float acc[2][4] = {};
  float mrun[2] = {-INFINITY, -INFINITY};
  float lrun[2] = {0.f, 0.f};
  const float scale = 0.17677669529663689f;  // 1/sqrt(32)

  for (int kc = 0; kc < le; kc += 64) {
    int nk = min(64, le - kc);
    {
      int r = tid >> 3;          // 0..31
      int c = (tid & 7) * 4;     // 0,4,...,28
#pragma unroll
      for (int it = 0; it < 2; ++it) {
        int rr = r + it * 32;
        float4 kv = make_float4(0.f, 0.f, 0.f, 0.f);
        float4 vv = make_float4(0.f, 0.f, 0.f, 0.f);
        if (rr < nk) {
          size_t base = (size_t)(es + kc + rr) * C_DIM + hd * HDIM + c;
          kv = *(const float4*)&k[base];
          vv = *(const float4*)&v[base];
        }
        KsT[c + 0][rr] = kv.x; KsT[c + 1][rr] = kv.y;
        KsT[c + 2][rr] = kv.z; KsT[c + 3][rr] = kv.w;
        *(float4*)&Vs[rr][c] = vv;
      }
      if (tid < 64) Mk[tid] = (tid < nk) ? emask[es + kc + tid] : 0;
    }
    __syncthreads();

    // ---- QK^T: p[r][t] = q_row_r . K_row(j*8+t), K operand read once, used for 2 rows
    float p[2][8] = {};
#pragma unroll 4
    for (int d = 0; d < 32; ++d) {
      float4 k0 = *(const float4*)&KsT[d][j * 8];
      float4 k1 = *(const float4*)&KsT[d][j * 8 + 4];
      float q0 = qreg[0][d], q1 = qreg[1][d];
      p[0][0] += q0 * k0.x; p[0][1] += q0 * k0.y; p[0][2] += q0 * k0.z; p[0][3] += q0 * k0.w;
      p[0][4] += q0 * k1.x; p[0][5] += q0 * k1.y; p[0][6] += q0 * k1.z; p[0][7] += q0 * k1.w;
      p[1][0] += q1 * k0.x; p[1][1] += q1 * k0.y; p[1][2] += q1 * k0.z; p[1][3] += q1 * k0.w;
      p[1][4] += q1 * k1.x; p[1][5] += q1 * k1.y; p[1][6] += q1 * k1.z; p[1][7] += q1 * k1.w;
    }

    int mk[8];
#pragma unroll
    for (int t = 0; t < 8; ++t) mk[t] = Mk[j * 8 + t];

    // ---- online softmax (per q-row; 8 lanes per row cooperate via shfl_xor 1,2,4)
#pragma unroll
    for (int r = 0; r < 2; ++r) {
      float mloc = -INFINITY;
#pragma unroll
      for (int t = 0; t < 8; ++t) {
        float s = mk[t] ? p[r][t] * scale : -INFINITY;
        p[r][t] = s;
        mloc = fmaxf(mloc, s);
      }
#pragma unroll
      for (int off = 1; off < 8; off <<= 1) mloc = fmaxf(mloc, __shfl_xor(mloc, off));
      float mnew = fmaxf(mrun[r], mloc);
      float alpha = (mnew == -INFINITY) ? 1.0f : __expf(mrun[r] - mnew);
      float pe[8];
      float lloc = 0.f;
#pragma unroll
      for (int t = 0; t < 8; ++t) {
        pe[t] = (p[r][t] == -INFINITY) ? 0.f : __expf(p[r][t] - mnew);
        lloc += pe[t];
      }
      *(float4*)&Ps[qg + r * 32][j * 8]     = make_float4(pe[0], pe[1], pe[2], pe[3]);
      *(float4*)&Ps[qg + r * 32][j * 8 + 4] = make_float4(pe[4], pe[5], pe[6], pe[7]);
#pragma unroll
      for (int off = 1; off < 8; off <<= 1) lloc += __shfl_xor(lloc, off);
      lrun[r] = lrun[r] * alpha + lloc;
      mrun[r] = mnew;
#pragma unroll
      for (int d = 0; d < 4; ++d) acc[r][d] *= alpha;
    }
    __syncthreads();

    // ---- PV: each Vs float4 read used for 2 rows; Ps read as float4 per 4 kk
#pragma unroll 4
    for (int kk4 = 0; kk4 < 16; ++kk4) {
      float pa[4], pb[4];
      *(float4*)pa = *(const float4*)&Ps[qg][kk4 * 4];
      *(float4*)pb = *(const float4*)&Ps[qg + 32][kk4 * 4];
#pragma unroll
      for (int u = 0; u < 4; ++u) {
        float4 vv = *(const float4*)&Vs[kk4 * 4 + u][j * 4];
        acc[0][0] += pa[u] * vv.x; acc[0][1] += pa[u] * vv.y;
        acc[0][2] += pa[u] * vv.z; acc[0][3] += pa[u] * vv.w;
        acc[1][0] += pb[u] * vv.x; acc[1][1] += pb[u] * vv.y;
        acc[1][2] += pb[u] * vv.z; acc[1][3] += pb[u] * vv.w;
      }
    }
    __syncthreads();
  }

#pragma unroll
  for (int r = 0; r < 2; ++r) {
    int qr = qt * 64 + qg + r * 32;
    if (qr < lx) {
      float invl = (lrun[r] > 0.f) ? 1.0f / lrun[r] : 0.f;
      float4 o = make_float4(acc[r][0] * invl, acc[r][1] * invl,
                             acc[r][2] * invl, acc[r][3] * invl);
      *(float4*)&y[(size_t)(xs + qr) * C_DIM + hd * HDIM + j * 4] = o;
    }
  }
}

// ---------------- launch ----------------
extern "C" void kernel_launch(void* const* d_in, const int* in_sizes, int n_in,
                              void* d_out, int out_size, void* d_ws, size_t ws_size,
                              hipStream_t stream) {
  const float* x    = (const float*)d_in[0];
  const int*   bx   = (const int*)d_in[1];
  const int*   be   = (const int*)d_in[2];
  const float* enc  = (const float*)d_in[3];
  const int*   msk  = (const int*)d_in[4];
  const float* Wq   = (const float*)d_in[5];
  const float* bq   = (const float*)d_in[6];
  const float* Wk   = (const float*)d_in[7];
  const float* bk   = (const float*)d_in[8];
  const float* Wv   = (const float*)d_in[9];
  const float* bv   = (const float*)d_in[10];
  const float* Wp   = (const float*)d_in[11];
  const float* bp   = (const float*)d_in[12];
  const float* W1   = (const float*)d_in[13];
  const float* b1   = (const float*)d_in[14];
  const float* W2   = (const float*)d_in[15];
  const float* b2   = (const float*)d_in[16];
  const float* lnw  = (const float*)d_in[17];
  const float* lnb  = (const float*)d_in[18];
  float* out = (float*)d_out;

  int Nx = in_sizes[0] / C_DIM;
  int Ne = in_sizes[3] / IN_DIM;
  int maxN = Nx > Ne ? Nx : Ne;

  char* ws = (char*)d_ws;
  int* sx = (int*)ws;          // 65 ints
  int* se = sx + 80;           // 65 ints
  float* R0 = (float*)(ws + 4096);              // Ne*512 floats (g, later k|v)
  float* g    = R0;
  float* kbuf = R0;
  float* vbuf = R0 + (size_t)Ne * C_DIM;
  float* R1 = R0 + (size_t)Ne * EMB_DIM;        // maxN*256 floats (h, later y)
  float* h    = R1;
  float* ybuf = R1;
  float* qbuf = R1 + (size_t)maxN * C_DIM;      // Nx*256 floats

  starts_kernel<<<1, 128, 0, stream>>>(bx, Nx, be, Ne, sx, se);

  // MLP: g = GELU(enc @ W1 + b1)   [Ne,512]
  gemm_kernel<1><<<dim3(EMB_DIM / 64, (Ne + 63) / 64), 256, 0, stream>>>(
      enc, W1, b1, g, Ne, EMB_DIM, IN_DIM);
  // h = g @ W2 + b2  [Ne,256], then LN
  gemm_kernel<0><<<dim3(C_DIM / 64, (Ne + 63) / 64), 256, 0, stream>>>(
      g, W2, b2, h, Ne, C_DIM, EMB_DIM);
  ln_kernel<<<(Ne + 3) / 4, 256, 0, stream>>>(h, lnw, lnb, Ne);

  // q = x @ Wq + bq ; k = h @ Wk + bk ; v = h @ Wv + bv
  gemm_kernel<0><<<dim3(C_DIM / 64, (Nx + 63) / 64), 256, 0, stream>>>(
      x, Wq, bq, qbuf, Nx, C_DIM, C_DIM);
  gemm_kernel<0><<<dim3(C_DIM / 64, (Ne + 63) / 64), 256, 0, stream>>>(
      h, Wk, bk, kbuf, Ne, C_DIM, C_DIM);
  gemm_kernel<0><<<dim3(C_DIM / 64, (Ne + 63) / 64), 256, 0, stream>>>(
      h, Wv, bv, vbuf, Ne, C_DIM, C_DIM);

  // attention -> ybuf (overwrites h region; h dead after k,v)
  attn_kernel<<<dim3(8, B_GROUPS, NHEADS), 256, 0, stream>>>(
      qbuf, kbuf, vbuf, sx, se, msk, ybuf);

  // out = y @ Wp + bp
  gemm_kernel<0><<<dim3(C_DIM / 64, (Nx + 63) / 64), 256, 0, stream>>>(
      ybuf, Wp, bp, out, Nx, C_DIM, C_DIM);
}